// Round 2
// baseline (80.206 us; speedup 1.0000x reference)
//
#include <hip/hip_runtime.h>
#include <hip/hip_bf16.h>
#include <math.h>

typedef __attribute__((ext_vector_type(8))) short short8;
typedef __attribute__((ext_vector_type(4))) short short4v;
typedef __attribute__((ext_vector_type(4))) float f32x4;

#define LOG2E 1.44269504088896340736f

__device__ __forceinline__ short bf16bits(float x) {
    __hip_bfloat16 b = __float2bfloat16(x);
    short r;
    __builtin_memcpy(&r, &b, 2);
    return r;
}

// ---------------- prep: f32 -> bf16 rows, row sq-norms, scale, zero accum ----
// One wave handles 4 rows: lane = sub(2b)*16 + q(4b); row = wid*4+sub,
// dims q*4..q*4+3 via float4 load, short4 bf16 store. 16-lane shfl reduce
// for the sq-norm. Also zeroes out_sum[n_test] and counters[n_groups].
__global__ __launch_bounds__(256) void kde_prep(
    const float* __restrict__ testX, const float* __restrict__ trainX,
    const float* __restrict__ w,
    __hip_bfloat16* __restrict__ testbf, __hip_bfloat16* __restrict__ trainbf,
    float* __restrict__ sqx, float* __restrict__ sqy, float* __restrict__ nhs,
    float* __restrict__ out_sum, int* __restrict__ counters,
    int n_test, int n_train, int n_groups)
{
    const int tid  = threadIdx.x;
    // zero accumulators + finalize counters (re-zeroed every call)
    const int zi = blockIdx.x * 256 + tid;
    if (zi < n_test) out_sum[zi] = 0.0f;
    else if (zi < n_test + n_groups) counters[zi - n_test] = 0;

    const int wid  = blockIdx.x * 4 + (tid >> 6);
    const int lane = tid & 63;
    const int sub  = lane >> 4;
    const int q    = lane & 15;
    const int row  = wid * 4 + sub;

    const float* src;
    __hip_bfloat16* dst;
    int r_local;
    if (row < n_test) { src = testX; dst = testbf; r_local = row; }
    else              { src = trainX; dst = trainbf; r_local = row - n_test; }
    if (row >= n_test + n_train) return;

    const float4 v = ((const float4*)src)[r_local * 16 + q];
    short4v b = { bf16bits(v.x), bf16bits(v.y), bf16bits(v.z), bf16bits(v.w) };
    *(short4v*)(dst + r_local * 64 + q * 4) = b;

    float s = v.x * v.x + v.y * v.y + v.z * v.z + v.w * v.w;
    #pragma unroll
    for (int m = 1; m < 16; m <<= 1) s += __shfl_xor(s, m);
    if (q == 0) {
        if (row < n_test) sqx[r_local] = s;
        else {
            sqy[r_local] = s;
            float ww = w[r_local];
            nhs[r_local] = -0.5f * LOG2E * ww * ww;  // p = exp2(dist2 * nhs)
        }
    }
}

// ---------------- main: MFMA cross-product + fused exp-sum + finalize -------
// Block: 16 test rows x 512 train cols. 4 waves; wave wv covers cols
// [blockIdx.y*512 + wv*128, +128) in 8 steps of 16. K=64 via 2 MFMAs.
// Fragments loaded directly from global (L2-resident bf16 rows):
//   A: lane(l&15) = test row, (l>>4)*8 = k-offset within 32-wide k-slice.
//   B: same packing (consistent A/B packing suffices for a full-K dot).
// C/D layout (HW-verified m89): col = l&15, row = (l>>4)*4 + reg.
// The last of the gridDim.y col-blocks per row-group (atomic counter)
// computes out = log(sum) - Z, replacing a third kernel.
__global__ __launch_bounds__(256) void kde_main(
    const __hip_bfloat16* __restrict__ testbf,
    const __hip_bfloat16* __restrict__ trainbf,
    const float* __restrict__ sqx, const float* __restrict__ sqy,
    const float* __restrict__ nhs, float* __restrict__ out_sum,
    int* __restrict__ counters, float* __restrict__ out, float Z)
{
    const int mbase = blockIdx.x * 16;
    const int wv    = threadIdx.x >> 6;
    const int lane  = threadIdx.x & 63;
    const int cg    = lane & 15;   // col selector / A-row selector
    const int kg    = lane >> 4;   // k-chunk selector

    // A fragments: test rows, hoisted out of the col loop.
    const int arow = mbase + cg;
    short8 a0 = *(const short8*)(testbf + arow * 64 +      kg * 8);
    short8 a1 = *(const short8*)(testbf + arow * 64 + 32 + kg * 8);

    // sq-norm of the 4 test rows this lane's accumulator covers.
    float sxr[4];
    #pragma unroll
    for (int r = 0; r < 4; ++r) sxr[r] = sqx[mbase + kg * 4 + r];

    float s[4] = {0.f, 0.f, 0.f, 0.f};
    const int colchunk = blockIdx.y * 512 + wv * 128;

    #pragma unroll
    for (int step = 0; step < 8; ++step) {
        const int bcol = colchunk + step * 16 + cg;
        short8 b0 = *(const short8*)(trainbf + bcol * 64 +      kg * 8);
        short8 b1 = *(const short8*)(trainbf + bcol * 64 + 32 + kg * 8);

        f32x4 acc = {0.f, 0.f, 0.f, 0.f};
        acc = __builtin_amdgcn_mfma_f32_16x16x32_bf16(a0, b0, acc, 0, 0, 0);
        acc = __builtin_amdgcn_mfma_f32_16x16x32_bf16(a1, b1, acc, 0, 0, 0);

        const float sy = sqy[bcol];
        const float nh = nhs[bcol];
        #pragma unroll
        for (int r = 0; r < 4; ++r) {
            float d2 = fmaxf(sxr[r] + sy - 2.0f * acc[r], 0.0f);
            s[r] += exp2f(d2 * nh);
        }
    }

    // Reduce across the 16 col lanes (xor bits 0..3 keep kg fixed).
    #pragma unroll
    for (int m = 1; m < 16; m <<= 1) {
        #pragma unroll
        for (int r = 0; r < 4; ++r) s[r] += __shfl_xor(s[r], m);
    }
    if (cg == 0) {
        #pragma unroll
        for (int r = 0; r < 4; ++r)
            atomicAdd(&out_sum[mbase + kg * 4 + r], s[r]);
    }

    // ---- last-col-block finalize (replaces a third kernel) ----
    __shared__ int sflag;
    __threadfence();          // release our partial sums
    __syncthreads();
    if (threadIdx.x == 0) {
        int old = atomicAdd(&counters[blockIdx.x], 1);
        sflag = (old == (int)gridDim.y - 1) ? 1 : 0;
    }
    __syncthreads();
    if (sflag && threadIdx.x < 16) {
        float ssum = __hip_atomic_load(&out_sum[mbase + threadIdx.x],
                                       __ATOMIC_RELAXED, __HIP_MEMORY_SCOPE_AGENT);
        out[mbase + threadIdx.x] = logf(ssum) - Z;
    }
}

extern "C" void kernel_launch(void* const* d_in, const int* in_sizes, int n_in,
                              void* d_out, int out_size, void* d_ws, size_t ws_size,
                              hipStream_t stream) {
    const float* testX  = (const float*)d_in[0];
    const float* trainX = (const float*)d_in[1];
    const float* w      = (const float*)d_in[2];
    float* out = (float*)d_out;

    const int d = 64;
    const int n_test  = in_sizes[0] / d;   // 2048
    const int n_train = in_sizes[1] / d;   // 4096
    const int n_groups = n_test / 16;      // 128 row-groups

    char* ws = (char*)d_ws;
    size_t off = 0;
    __hip_bfloat16* testbf  = (__hip_bfloat16*)(ws + off); off += (size_t)n_test  * d * 2;
    __hip_bfloat16* trainbf = (__hip_bfloat16*)(ws + off); off += (size_t)n_train * d * 2;
    float* sqx     = (float*)(ws + off); off += (size_t)n_test  * 4;
    float* sqy     = (float*)(ws + off); off += (size_t)n_train * 4;
    float* nhs     = (float*)(ws + off); off += (size_t)n_train * 4;
    float* out_sum = (float*)(ws + off); off += (size_t)n_test  * 4;
    int*   counters = (int*)(ws + off);  off += (size_t)n_groups * 4;
    (void)ws_size; (void)n_in; (void)out_size;

    const float Z = 0.5f * d * logf(2.0f * (float)M_PI) + logf((float)n_train);

    const int rows = n_test + n_train;                 // 6144
    kde_prep<<<rows / 16, 256, 0, stream>>>(
        testX, trainX, w, testbf, trainbf, sqx, sqy, nhs,
        out_sum, counters, n_test, n_train, n_groups);

    dim3 grid(n_groups, n_train / 512);
    kde_main<<<grid, 256, 0, stream>>>(
        testbf, trainbf, sqx, sqy, nhs, out_sum, counters, out, Z);
}

// Round 4
// 28.528 us; speedup vs baseline: 2.8115x; 2.8115x over previous
//
#include <hip/hip_runtime.h>
#include <hip/hip_bf16.h>
#include <math.h>

typedef __attribute__((ext_vector_type(8))) short short8;
typedef __attribute__((ext_vector_type(4))) short short4v;
typedef __attribute__((ext_vector_type(4))) float f32x4;

#define LOG2E 1.44269504088896340736f

__device__ __forceinline__ short bf16bits(float x) {
    __hip_bfloat16 b = __float2bfloat16(x);
    short r;
    __builtin_memcpy(&r, &b, 2);
    return r;
}

// ---------------- prep: f32 -> bf16 rows, row sq-norms, packed col params ----
// One wave handles 4 rows: lane = sub(2b)*16 + q(4b); row = wid*4+sub,
// dims q*4..q*4+3 via float4 load, short4 bf16 store. 16-lane shfl reduce
// for the sq-norm. Train rows also emit snh[j] = {||y||^2, -0.5*log2e*w^2}.
__global__ __launch_bounds__(256) void kde_prep(
    const float* __restrict__ testX, const float* __restrict__ trainX,
    const float* __restrict__ w,
    __hip_bfloat16* __restrict__ testbf, __hip_bfloat16* __restrict__ trainbf,
    float* __restrict__ sqx, float2* __restrict__ snh,
    int n_test, int n_train)
{
    const int tid  = threadIdx.x;
    const int wid  = blockIdx.x * 4 + (tid >> 6);
    const int lane = tid & 63;
    const int sub  = lane >> 4;
    const int q    = lane & 15;
    const int row  = wid * 4 + sub;
    if (row >= n_test + n_train) return;

    const float* src;
    __hip_bfloat16* dst;
    int r_local;
    if (row < n_test) { src = testX;  dst = testbf;  r_local = row; }
    else              { src = trainX; dst = trainbf; r_local = row - n_test; }

    const float4 v = ((const float4*)src)[r_local * 16 + q];
    short4v b = { bf16bits(v.x), bf16bits(v.y), bf16bits(v.z), bf16bits(v.w) };
    *(short4v*)(dst + r_local * 64 + q * 4) = b;

    float s = v.x * v.x + v.y * v.y + v.z * v.z + v.w * v.w;
    #pragma unroll
    for (int m = 1; m < 16; m <<= 1) s += __shfl_xor(s, m);
    if (q == 0) {
        if (row < n_test) sqx[r_local] = s;
        else {
            float ww = w[r_local];
            snh[r_local] = make_float2(s, -0.5f * LOG2E * ww * ww);
        }
    }
}

// ---------------- main: MFMA cross-product + fused exp-sum + in-block LSE ---
// One block per 16 test rows (grid = n_test/16 = 128). 1024 threads = 16
// waves, 4 waves/SIMD. Wave wv covers train cols [wv*256, wv*256+256) in 16
// steps of 16 cols. K=64 via 2 chained mfma_f32_16x16x32_bf16.
// Fragments loaded directly from global (all data L2-resident; no staging —
// Common-mistake #7):
//   A: lane(l&15) = test row, k-chunk (l>>4)*8 within each 32-wide k slice.
//   B: identical packing (any k-bijection applied to BOTH A and B preserves
//      the dot product). C/D layout (HW-verified m89): col=l&15,
//      row=(l>>4)*4+reg.
// Per-wave row partials -> 1KB LDS -> threads 0..15 finish log(sum)-Z.
// No atomics, no fences, no cross-block traffic.
__global__ __launch_bounds__(1024) void kde_main(
    const __hip_bfloat16* __restrict__ testbf,
    const __hip_bfloat16* __restrict__ trainbf,
    const float* __restrict__ sqx, const float2* __restrict__ snh,
    float* __restrict__ out, float Z)
{
    __shared__ float lds[16 * 16];   // [row][wave]

    const int mbase = blockIdx.x * 16;
    const int wv    = threadIdx.x >> 6;   // 0..15
    const int lane  = threadIdx.x & 63;
    const int cg    = lane & 15;          // col selector / A-row selector
    const int kg    = lane >> 4;          // k-chunk selector

    // A fragments: test rows, hoisted out of the col loop.
    const int arow = mbase + cg;
    const short8 a0 = *(const short8*)(testbf + arow * 64 +      kg * 8);
    const short8 a1 = *(const short8*)(testbf + arow * 64 + 32 + kg * 8);

    // sq-norm of the 4 test rows this lane's accumulator covers.
    float sxr[4];
    #pragma unroll
    for (int r = 0; r < 4; ++r) sxr[r] = sqx[mbase + kg * 4 + r];

    float s[4] = {0.f, 0.f, 0.f, 0.f};

    #pragma unroll 4
    for (int step = 0; step < 16; ++step) {
        const int bcol = wv * 256 + step * 16 + cg;
        const short8 b0 = *(const short8*)(trainbf + bcol * 64 +      kg * 8);
        const short8 b1 = *(const short8*)(trainbf + bcol * 64 + 32 + kg * 8);
        const float2 p  = snh[bcol];      // {||y||^2, -0.5*log2e*w^2}

        f32x4 acc = {0.f, 0.f, 0.f, 0.f};
        acc = __builtin_amdgcn_mfma_f32_16x16x32_bf16(a0, b0, acc, 0, 0, 0);
        acc = __builtin_amdgcn_mfma_f32_16x16x32_bf16(a1, b1, acc, 0, 0, 0);

        #pragma unroll
        for (int r = 0; r < 4; ++r) {
            float d2 = fmaxf(sxr[r] + p.x - 2.0f * acc[r], 0.0f);
            s[r] += __builtin_exp2f(d2 * p.y);
        }
    }

    // Reduce across the 16 col lanes (xor bits 0..3 keep kg fixed).
    #pragma unroll
    for (int m = 1; m < 16; m <<= 1) {
        #pragma unroll
        for (int r = 0; r < 4; ++r) s[r] += __shfl_xor(s[r], m);
    }
    if (cg == 0) {
        #pragma unroll
        for (int r = 0; r < 4; ++r)
            lds[(kg * 4 + r) * 16 + wv] = s[r];
    }
    __syncthreads();

    if (threadIdx.x < 16) {
        const int r = threadIdx.x;
        float sum = 0.f;
        #pragma unroll
        for (int v = 0; v < 16; ++v) sum += lds[r * 16 + v];
        out[mbase + r] = __logf(sum) - Z;
    }
}

extern "C" void kernel_launch(void* const* d_in, const int* in_sizes, int n_in,
                              void* d_out, int out_size, void* d_ws, size_t ws_size,
                              hipStream_t stream) {
    const float* testX  = (const float*)d_in[0];
    const float* trainX = (const float*)d_in[1];
    const float* w      = (const float*)d_in[2];
    float* out = (float*)d_out;

    const int d = 64;
    const int n_test  = in_sizes[0] / d;   // 2048
    const int n_train = in_sizes[1] / d;   // 4096

    char* ws = (char*)d_ws;
    size_t off = 0;
    __hip_bfloat16* testbf  = (__hip_bfloat16*)(ws + off); off += (size_t)n_test  * d * 2;
    __hip_bfloat16* trainbf = (__hip_bfloat16*)(ws + off); off += (size_t)n_train * d * 2;
    float*  sqx = (float*)(ws + off);  off += (size_t)n_test * 4;
    float2* snh = (float2*)(ws + off); off += (size_t)n_train * 8;
    (void)ws_size; (void)n_in; (void)out_size;

    const float Z = 0.5f * d * logf(2.0f * (float)M_PI) + logf((float)n_train);

    const int rows = n_test + n_train;                 // 6144
    kde_prep<<<rows / 16, 256, 0, stream>>>(
        testX, trainX, w, testbf, trainbf, sqx, snh, n_test, n_train);

    kde_main<<<n_test / 16, 1024, 0, stream>>>(
        testbf, trainbf, sqx, snh, out, Z);
}

// Round 5
// 24.232 us; speedup vs baseline: 3.3100x; 1.1773x over previous
//
#include <hip/hip_runtime.h>
#include <hip/hip_bf16.h>
#include <math.h>

typedef __attribute__((ext_vector_type(8))) short short8;
typedef __attribute__((ext_vector_type(4))) short short4v;
typedef __attribute__((ext_vector_type(4))) float f32x4;

#define LOG2E 1.44269504088896340736f

__device__ __forceinline__ short bf16bits(float x) {
    __hip_bfloat16 b = __float2bfloat16(x);
    short r;
    __builtin_memcpy(&r, &b, 2);
    return r;
}

// ---------------- prep: f32 -> bf16 rows, row sq-norms, packed col params ----
// One wave handles 4 rows: lane = sub(2b)*16 + q(4b); row = wid*4+sub,
// dims q*4..q*4+3 via float4 load, short4 bf16 store. 16-lane shfl reduce
// for the sq-norm. Train rows also emit snh[j] = {||y||^2, -0.5*log2e*w^2}.
__global__ __launch_bounds__(256) void kde_prep(
    const float* __restrict__ testX, const float* __restrict__ trainX,
    const float* __restrict__ w,
    __hip_bfloat16* __restrict__ testbf, __hip_bfloat16* __restrict__ trainbf,
    float* __restrict__ sqx, float2* __restrict__ snh,
    int n_test, int n_train)
{
    const int tid  = threadIdx.x;
    const int wid  = blockIdx.x * 4 + (tid >> 6);
    const int lane = tid & 63;
    const int sub  = lane >> 4;
    const int q    = lane & 15;
    const int row  = wid * 4 + sub;
    if (row >= n_test + n_train) return;

    const float* src;
    __hip_bfloat16* dst;
    int r_local;
    if (row < n_test) { src = testX;  dst = testbf;  r_local = row; }
    else              { src = trainX; dst = trainbf; r_local = row - n_test; }

    const float4 v = ((const float4*)src)[r_local * 16 + q];
    short4v b = { bf16bits(v.x), bf16bits(v.y), bf16bits(v.z), bf16bits(v.w) };
    *(short4v*)(dst + r_local * 64 + q * 4) = b;

    float s = v.x * v.x + v.y * v.y + v.z * v.z + v.w * v.w;
    #pragma unroll
    for (int m = 1; m < 16; m <<= 1) s += __shfl_xor(s, m);
    if (q == 0) {
        if (row < n_test) sqx[r_local] = s;
        else {
            float ww = w[r_local];
            snh[r_local] = make_float2(s, -0.5f * LOG2E * ww * ww);
        }
    }
}

// ---------------- main: MFMA cross-product + fused exp-sum, partial out -----
// Grid (n_test/16 row-groups, n_train/1024 col-chunks) = 512 blocks x 1024
// threads (16 waves) -> 8 waves/SIMD across ALL 256 CUs. Wave wv covers cols
// [cc*1024 + wv*64, +64) in 4 steps of 16 cols (short serial chain). K=64
// via 2 chained mfma_f32_16x16x32_bf16, fragments straight from global
// (L2-resident; no LDS staging). A: lane(l&15)=test row, k-chunk (l>>4)*8;
// B: identical packing (consistent A/B k-bijection preserves the dot).
// C/D layout (HW-verified m89): col=l&15, row=(l>>4)*4+reg.
// Block reduces 16 wave-partials via 1KB LDS, writes 16 floats to
// partial[cc][row]. No atomics, no fences, no cross-block visibility needs.
__global__ __launch_bounds__(1024) void kde_main(
    const __hip_bfloat16* __restrict__ testbf,
    const __hip_bfloat16* __restrict__ trainbf,
    const float* __restrict__ sqx, const float2* __restrict__ snh,
    float* __restrict__ partial, int n_test)
{
    __shared__ float lds[16 * 16];   // [row][wave]

    const int mbase = blockIdx.x * 16;
    const int cc    = blockIdx.y;
    const int wv    = threadIdx.x >> 6;   // 0..15
    const int lane  = threadIdx.x & 63;
    const int cg    = lane & 15;          // col selector / A-row selector
    const int kg    = lane >> 4;          // k-chunk selector

    // A fragments: test rows, hoisted out of the col loop.
    const int arow = mbase + cg;
    const short8 a0 = *(const short8*)(testbf + arow * 64 +      kg * 8);
    const short8 a1 = *(const short8*)(testbf + arow * 64 + 32 + kg * 8);

    // sq-norm of the 4 test rows this lane's accumulator covers.
    float sxr[4];
    #pragma unroll
    for (int r = 0; r < 4; ++r) sxr[r] = sqx[mbase + kg * 4 + r];

    float s[4] = {0.f, 0.f, 0.f, 0.f};
    const int colbase = cc * 1024 + wv * 64;

    #pragma unroll
    for (int step = 0; step < 4; ++step) {
        const int bcol = colbase + step * 16 + cg;
        const short8 b0 = *(const short8*)(trainbf + bcol * 64 +      kg * 8);
        const short8 b1 = *(const short8*)(trainbf + bcol * 64 + 32 + kg * 8);
        const float2 p  = snh[bcol];      // {||y||^2, -0.5*log2e*w^2}

        f32x4 acc = {0.f, 0.f, 0.f, 0.f};
        acc = __builtin_amdgcn_mfma_f32_16x16x32_bf16(a0, b0, acc, 0, 0, 0);
        acc = __builtin_amdgcn_mfma_f32_16x16x32_bf16(a1, b1, acc, 0, 0, 0);

        #pragma unroll
        for (int r = 0; r < 4; ++r) {
            float d2 = fmaxf(__builtin_fmaf(-2.0f, acc[r], sxr[r] + p.x), 0.0f);
            s[r] += __builtin_exp2f(d2 * p.y);
        }
    }

    // Reduce across the 16 col lanes (xor bits 0..3 keep kg fixed).
    #pragma unroll
    for (int m = 1; m < 16; m <<= 1) {
        #pragma unroll
        for (int r = 0; r < 4; ++r) s[r] += __shfl_xor(s[r], m);
    }
    if (cg == 0) {
        #pragma unroll
        for (int r = 0; r < 4; ++r)
            lds[(kg * 4 + r) * 16 + wv] = s[r];
    }
    __syncthreads();

    if (threadIdx.x < 16) {
        const int r = threadIdx.x;
        float sum = 0.f;
        #pragma unroll
        for (int v = 0; v < 16; ++v) sum += lds[r * 16 + v];
        partial[cc * n_test + mbase + r] = sum;
    }
}

// ---------------- final: combine col-chunk partials, log, -Z ----------------
__global__ __launch_bounds__(256) void kde_final(
    const float* __restrict__ partial, float* __restrict__ out,
    float Z, int n_test, int n_cc)
{
    const int i = blockIdx.x * 256 + threadIdx.x;
    if (i >= n_test) return;
    float sum = 0.f;
    for (int c = 0; c < n_cc; ++c) sum += partial[c * n_test + i];
    out[i] = __logf(sum) - Z;
}

extern "C" void kernel_launch(void* const* d_in, const int* in_sizes, int n_in,
                              void* d_out, int out_size, void* d_ws, size_t ws_size,
                              hipStream_t stream) {
    const float* testX  = (const float*)d_in[0];
    const float* trainX = (const float*)d_in[1];
    const float* w      = (const float*)d_in[2];
    float* out = (float*)d_out;

    const int d = 64;
    const int n_test  = in_sizes[0] / d;   // 2048
    const int n_train = in_sizes[1] / d;   // 4096
    const int n_cc    = n_train / 1024;    // 4 col-chunks

    char* ws = (char*)d_ws;
    size_t off = 0;
    __hip_bfloat16* testbf  = (__hip_bfloat16*)(ws + off); off += (size_t)n_test  * d * 2;
    __hip_bfloat16* trainbf = (__hip_bfloat16*)(ws + off); off += (size_t)n_train * d * 2;
    float*  sqx     = (float*)(ws + off);  off += (size_t)n_test * 4;
    float2* snh     = (float2*)(ws + off); off += (size_t)n_train * 8;
    float*  partial = (float*)(ws + off);  off += (size_t)n_cc * n_test * 4;
    (void)ws_size; (void)n_in; (void)out_size;

    const float Z = 0.5f * d * logf(2.0f * (float)M_PI) + logf((float)n_train);

    const int rows = n_test + n_train;                 // 6144
    kde_prep<<<rows / 16, 256, 0, stream>>>(
        testX, trainX, w, testbf, trainbf, sqx, snh, n_test, n_train);

    dim3 grid(n_test / 16, n_cc);
    kde_main<<<grid, 1024, 0, stream>>>(
        testbf, trainbf, sqx, snh, partial, n_test);

    kde_final<<<(n_test + 255) / 256, 256, 0, stream>>>(
        partial, out, Z, n_test, n_cc);
}